// Round 1
// baseline (402.571 us; speedup 1.0000x reference)
//
#include <hip/hip_runtime.h>
#include <hip/hip_bf16.h>
#include <math.h>

#define DEV __device__ __forceinline__

typedef __bf16 bf16;
typedef __bf16 bf16x8 __attribute__((ext_vector_type(8)));
typedef float f32x4 __attribute__((ext_vector_type(4)));

DEV f32x4 zero4() { f32x4 z; z[0]=0.f; z[1]=0.f; z[2]=0.f; z[3]=0.f; return z; }

// ---------------------------------------------------------------------------
// Geometry: B=2, C=192, T=8, H=56, W=56; window (2,7,7) N=98; shift (1,3,3)
// windows: 4*8*8=256 per batch, B_=512; tokens M = 50176
// ---------------------------------------------------------------------------

// K0: transpose weights to (N,K) k-contiguous bf16
__global__ __launch_bounds__(256) void prep_w_k(
    const float* __restrict__ qw, const float* __restrict__ pw,
    const float* __restrict__ f1, const float* __restrict__ f2,
    bf16* __restrict__ qwt, bf16* __restrict__ pwt,
    bf16* __restrict__ f1t, bf16* __restrict__ f2t)
{
    int i = blockIdx.x * 256 + threadIdx.x;
    if (i < 576*192) { int n = i / 192, k = i % 192; qwt[i] = (bf16)qw[(size_t)k*576 + n]; }
    if (i < 192*192) { int n = i / 192, k = i % 192; pwt[i] = (bf16)pw[(size_t)k*192 + n]; }
    if (i < 768*192) { int n = i / 192, k = i % 192; f1t[i] = (bf16)f1[(size_t)k*768 + n]; }
    if (i < 192*768) { int n = i / 768, k = i % 768; f2t[i] = (bf16)f2[(size_t)k*192 + n]; }
}

// K1: LN1 + cyclic shift + window partition. grid = B*T*H = 896, block 256.
// block handles output-domain (b, ts, hs) row of 56 w positions x 192 ch.
__global__ __launch_bounds__(256) void ln1_window_k(
    const float* __restrict__ x, const float* __restrict__ g,
    const float* __restrict__ bta, bf16* __restrict__ xw)
{
    __shared__ float tile[56*193];
    __shared__ float mu[56], rs[56];
    int blk = blockIdx.x;
    int bb = blk / 448; int r = blk % 448; int ts = r / 56; int hs = r % 56;
    int t = (ts + 1) & 7;
    int h = hs + 3; if (h >= 56) h -= 56;
    int tid = threadIdx.x;
    const float* xs = x + ((size_t)bb*1536 + t)*3136 + h*56;   // + c*25088 + w
    for (int e = tid; e < 192*56; e += 256) {
        int c = e / 56, w = e % 56;
        int wsp = w - 3; if (wsp < 0) wsp += 56;               // shifted position
        tile[wsp*193 + c] = xs[(size_t)c*25088 + w];
    }
    __syncthreads();
    if (tid < 56) {
        float s = 0.f, s2 = 0.f;
        for (int c = 0; c < 192; c++) { float v = tile[tid*193 + c]; s += v; s2 += v*v; }
        float m = s * (1.0f/192.0f);
        float var = s2 * (1.0f/192.0f) - m*m;
        mu[tid] = m; rs[tid] = rsqrtf(var + 1e-5f);
    }
    __syncthreads();
    int tb = ts >> 1, wt = ts & 1;
    int hb = hs / 7, wh = hs % 7;
    for (int e = tid; e < 56*192; e += 256) {
        int wpos = e / 192, c = e % 192;
        float v = (tile[wpos*193 + c] - mu[wpos]) * rs[wpos] * g[c] + bta[c];
        int wb = wpos / 7, ww = wpos % 7;
        int widx = bb*256 + tb*64 + hb*8 + wb;
        int n = wt*49 + wh*7 + ww;
        xw[((size_t)widx*98 + n)*192 + c] = (bf16)v;
    }
}

// Generic bf16 MFMA GEMM: C(M,NT) = A(M,KT) @ BT(NT,KT)^T + bias, M=50176.
// BM=128 BN=64 BK=64, 4 waves (2x2), each wave 64x32 out = 4x2 16x16 tiles.
// EPI: 0 = store bf16; 1 = store f32; 2 = exact GELU, store bf16;
//      3 = add resid, store f32.
template<int KT, int NT, int EPI>
__global__ __launch_bounds__(256) void gemm_k(
    const bf16* __restrict__ A, const bf16* __restrict__ BT,
    const float* __restrict__ bias, const float* __restrict__ resid,
    void* __restrict__ outp)
{
    __shared__ bf16 la[128*72];
    __shared__ bf16 lb[64*72];
    constexpr int NTILES = NT / 64;
    int bid = blockIdx.x;
    int m0 = (bid / NTILES) * 128;
    int n0 = (bid % NTILES) * 64;
    int tid = threadIdx.x;
    int lane = tid & 63;
    int wv = tid >> 6;
    int wr = wv >> 1, wc = wv & 1;
    int l15 = lane & 15, lg = lane >> 4;

    f32x4 acc[4][2];
    #pragma unroll
    for (int i = 0; i < 4; i++)
        #pragma unroll
        for (int j = 0; j < 2; j++) acc[i][j] = zero4();

    for (int kb = 0; kb < KT; kb += 64) {
        #pragma unroll
        for (int tt = 0; tt < 4; tt++) {
            int e = tid + tt*256;              // 1024 chunks of 8 bf16
            int row = e >> 3, ck = e & 7;
            *(bf16x8*)&la[row*72 + ck*8] =
                *(const bf16x8*)&A[(size_t)(m0 + row)*KT + kb + ck*8];
        }
        #pragma unroll
        for (int tt = 0; tt < 2; tt++) {
            int e = tid + tt*256;              // 512 chunks
            int row = e >> 3, ck = e & 7;
            *(bf16x8*)&lb[row*72 + ck*8] =
                *(const bf16x8*)&BT[(size_t)(n0 + row)*KT + kb + ck*8];
        }
        __syncthreads();
        #pragma unroll
        for (int ks = 0; ks < 64; ks += 32) {
            bf16x8 af[4], bfr[2];
            #pragma unroll
            for (int i = 0; i < 4; i++)
                af[i] = *(const bf16x8*)&la[(wr*64 + i*16 + l15)*72 + ks + lg*8];
            #pragma unroll
            for (int j = 0; j < 2; j++)
                bfr[j] = *(const bf16x8*)&lb[(wc*32 + j*16 + l15)*72 + ks + lg*8];
            #pragma unroll
            for (int i = 0; i < 4; i++)
                #pragma unroll
                for (int j = 0; j < 2; j++)
                    acc[i][j] = __builtin_amdgcn_mfma_f32_16x16x32_bf16(af[i], bfr[j], acc[i][j], 0, 0, 0);
        }
        __syncthreads();
    }

    #pragma unroll
    for (int i = 0; i < 4; i++) {
        #pragma unroll
        for (int j = 0; j < 2; j++) {
            #pragma unroll
            for (int r = 0; r < 4; r++) {
                int row = m0 + wr*64 + i*16 + lg*4 + r;
                int col = n0 + wc*32 + j*16 + l15;
                float v = acc[i][j][r] + bias[col];
                size_t oidx = (size_t)row * NT + col;
                if constexpr (EPI == 0) {
                    ((bf16*)outp)[oidx] = (bf16)v;
                } else if constexpr (EPI == 1) {
                    ((float*)outp)[oidx] = v;
                } else if constexpr (EPI == 2) {
                    float gl = 0.5f * v * (1.0f + erff(v * 0.70710678118654752f));
                    ((bf16*)outp)[oidx] = (bf16)gl;
                } else {
                    ((float*)outp)[oidx] = v + resid[oidx];
                }
            }
        }
    }
}

// K3: attention per (window, head). grid = 512*6 = 3072, block 256 (4 waves).
// N=98 padded to 112 rows (7 tiles), keys padded to 128 for PV K-loop.
__global__ __launch_bounds__(256) void attn_k(
    const bf16* __restrict__ qkv, const float* __restrict__ rpb,
    const float* __restrict__ maskm, bf16* __restrict__ aout)
{
    __shared__ bf16 Qs[112*40];
    __shared__ bf16 Ks[112*40];
    __shared__ bf16 VT[32*136];    // [d][key], keys 98..127 zero
    __shared__ bf16 Pl[112*136];   // [q][key] probabilities, keys 112..127 zero
    int blk = blockIdx.x;
    int b_ = blk / 6, head = blk % 6;
    int tid = threadIdx.x, lane = tid & 63, wv = tid >> 6;
    int l15 = lane & 15, lg = lane >> 4;
    const bf16* base = qkv + (size_t)b_*98*576 + head*32;

    // zero VT and Pl (dword stores)
    {
        unsigned int* z1 = (unsigned int*)VT;
        unsigned int* z2 = (unsigned int*)Pl;
        for (int e = tid; e < (32*136)/2; e += 256) z1[e] = 0u;
        for (int e = tid; e < (112*136)/2; e += 256) z2[e] = 0u;
    }
    __syncthreads();
    // stage Q, K (row-major, pad 40) and V transposed
    for (int e = tid; e < 98*4; e += 256) {
        int n = e >> 2, q = e & 3;
        bf16x8 qa = *(const bf16x8*)&base[(size_t)n*576 + q*8];
        bf16x8 ka = *(const bf16x8*)&base[(size_t)n*576 + 192 + q*8];
        bf16x8 va = *(const bf16x8*)&base[(size_t)n*576 + 384 + q*8];
        *(bf16x8*)&Qs[n*40 + q*8] = qa;
        *(bf16x8*)&Ks[n*40 + q*8] = ka;
        #pragma unroll
        for (int j = 0; j < 8; j++) VT[(q*8 + j)*136 + n] = va[j];
    }
    __syncthreads();

    const float scale = 0.17677669529663687f;  // 32^-0.5
    int wib = b_ & 255;                         // window index within batch

    for (int rt = wv; rt < 7; rt += 4) {
        // ---- S = Q @ K^T ----
        f32x4 sacc[7];
        #pragma unroll
        for (int j = 0; j < 7; j++) sacc[j] = zero4();
        bf16x8 qf = *(const bf16x8*)&Qs[(rt*16 + l15)*40 + lg*8];
        #pragma unroll
        for (int j = 0; j < 7; j++) {
            bf16x8 kf = *(const bf16x8*)&Ks[(j*16 + l15)*40 + lg*8];
            sacc[j] = __builtin_amdgcn_mfma_f32_16x16x32_bf16(qf, kf, sacc[j], 0, 0, 0);
        }
        // ---- softmax rows (each row lives in one 16-lane group) ----
        #pragma unroll
        for (int r = 0; r < 4; r++) {
            int nq = rt*16 + lg*4 + r;
            int t1 = nq / 49, r1 = nq % 49, h1 = r1 / 7, w1 = r1 % 7;
            float sv[7];
            float m = -1e30f;
            #pragma unroll
            for (int j = 0; j < 7; j++) {
                int nk = j*16 + l15;
                float v = sacc[j][r] * scale;
                if (nk < 98 && nq < 98) {
                    int t2 = nk / 49, r2 = nk % 49, h2 = r2 / 7, w2 = r2 % 7;
                    int idx = (t1 - t2 + 1)*169 + (h1 - h2 + 6)*13 + (w1 - w2 + 6);
                    v += rpb[idx*6 + head] + maskm[((size_t)wib*98 + nq)*98 + nk];
                }
                if (nk >= 98) v = -1e30f;
                sv[j] = v;
                m = fmaxf(m, v);
            }
            #pragma unroll
            for (int d = 1; d < 16; d <<= 1) m = fmaxf(m, __shfl_xor(m, d));
            float sum = 0.f;
            #pragma unroll
            for (int j = 0; j < 7; j++) {
                float p = __expf(sv[j] - m);
                if ((j*16 + l15) >= 98) p = 0.f;
                sv[j] = p; sum += p;
            }
            #pragma unroll
            for (int d = 1; d < 16; d <<= 1) sum += __shfl_xor(sum, d);
            float inv = 1.0f / sum;
            #pragma unroll
            for (int j = 0; j < 7; j++)
                Pl[nq*136 + j*16 + l15] = (bf16)(sv[j] * inv);
        }
        // ---- O = P @ V ----
        #pragma unroll
        for (int dt = 0; dt < 2; dt++) {
            f32x4 oacc = zero4();
            #pragma unroll
            for (int kc = 0; kc < 4; kc++) {
                bf16x8 pf = *(const bf16x8*)&Pl[(rt*16 + l15)*136 + kc*32 + lg*8];
                bf16x8 vf = *(const bf16x8*)&VT[(dt*16 + l15)*136 + kc*32 + lg*8];
                oacc = __builtin_amdgcn_mfma_f32_16x16x32_bf16(pf, vf, oacc, 0, 0, 0);
            }
            #pragma unroll
            for (int r = 0; r < 4; r++) {
                int row = rt*16 + lg*4 + r;
                if (row < 98)
                    aout[((size_t)b_*98 + row)*192 + head*32 + dt*16 + l15] = (bf16)oacc[r];
            }
        }
    }
}

// K5: window reverse + roll-back + residual(x) + LN2. grid 896.
__global__ __launch_bounds__(256) void rev_res_ln2_k(
    const float* __restrict__ x, const float* __restrict__ pw,
    const float* __restrict__ g2, const float* __restrict__ b2,
    float* __restrict__ x1, bf16* __restrict__ xn2)
{
    __shared__ float tile[56*193];
    __shared__ float mu[56], rs[56];
    int blk = blockIdx.x;
    int bb = blk / 448; int r = blk % 448; int t = r / 56; int h = r % 56;
    int ts = (t + 7) & 7;
    int hs = h - 3; if (hs < 0) hs += 56;
    int tid = threadIdx.x;
    const float* xs = x + ((size_t)bb*1536 + t)*3136 + h*56;
    for (int e = tid; e < 192*56; e += 256) {
        int c = e / 56, w = e % 56;
        tile[w*193 + c] = xs[(size_t)c*25088 + w];
    }
    __syncthreads();
    int tb = ts >> 1, wt = ts & 1, hb = hs / 7, wh = hs % 7;
    for (int e = tid; e < 56*192; e += 256) {
        int w = e / 192, c = e % 192;
        int wsp = w - 3; if (wsp < 0) wsp += 56;
        int wb = wsp / 7, ww = wsp % 7;
        size_t tok = (size_t)(bb*256 + tb*64 + hb*8 + wb)*98 + wt*49 + wh*7 + ww;
        tile[w*193 + c] += pw[tok*192 + c];
    }
    __syncthreads();
    if (tid < 56) {
        float s = 0.f, s2 = 0.f;
        for (int c = 0; c < 192; c++) { float v = tile[tid*193 + c]; s += v; s2 += v*v; }
        float m = s * (1.0f/192.0f);
        float var = s2 * (1.0f/192.0f) - m*m;
        mu[tid] = m; rs[tid] = rsqrtf(var + 1e-5f);
    }
    __syncthreads();
    size_t tok0 = ((size_t)(bb*8 + t)*56 + h)*56;
    for (int e = tid; e < 56*192; e += 256) {
        int w = e / 192, c = e % 192;
        float v = tile[w*193 + c];
        x1[(tok0 + w)*192 + c] = v;
        xn2[(tok0 + w)*192 + c] = (bf16)((v - mu[w]) * rs[w] * g2[c] + b2[c]);
    }
}

// K8: channel-last -> channel-first transpose of final x2. grid 896.
__global__ __launch_bounds__(256) void transpose_out_k(
    const float* __restrict__ xin, float* __restrict__ out)
{
    __shared__ float tile[192*57];
    int blk = blockIdx.x;
    int bb = blk / 448; int r = blk % 448; int t = r / 56; int h = r % 56;
    int tid = threadIdx.x;
    const float* rowp = xin + ((size_t)(bb*8 + t)*56 + h)*56*192;
    for (int e = tid; e < 56*192; e += 256) {
        int w = e / 192, c = e % 192;
        tile[c*57 + w] = rowp[e];
    }
    __syncthreads();
    float* op = out + (size_t)bb*192*25088 + (size_t)t*3136 + h*56;
    for (int e = tid; e < 192*56; e += 256) {
        int c = e / 56, w = e % 56;
        op[(size_t)c*25088 + w] = tile[c*57 + w];
    }
}

// ---------------------------------------------------------------------------
extern "C" void kernel_launch(void* const* d_in, const int* in_sizes, int n_in,
                              void* d_out, int out_size, void* d_ws, size_t ws_size,
                              hipStream_t stream)
{
    const float* x     = (const float*)d_in[0];
    const float* maskm = (const float*)d_in[1];
    const float* n1g   = (const float*)d_in[2];
    const float* n1b   = (const float*)d_in[3];
    const float* qkvw  = (const float*)d_in[4];
    const float* qkvb  = (const float*)d_in[5];
    const float* projw = (const float*)d_in[6];
    const float* projb = (const float*)d_in[7];
    const float* rpb   = (const float*)d_in[8];
    const float* n2g   = (const float*)d_in[9];
    const float* n2b   = (const float*)d_in[10];
    const float* f1w   = (const float*)d_in[11];
    const float* f1b   = (const float*)d_in[12];
    const float* f2w   = (const float*)d_in[13];
    const float* f2b   = (const float*)d_in[14];

    char* ws = (char*)d_ws;
    // weights (transposed bf16), < 1 MB
    bf16* qkv_wt = (bf16*)(ws + 0);
    bf16* proj_wt = (bf16*)(ws + 221184);
    bf16* fc1_wt  = (bf16*)(ws + 294912);
    bf16* fc2_wt  = (bf16*)(ws + 589824);
    // region A: xw (bf16, 19.27MB) -> reused as attn_out
    bf16* xw   = (bf16*)(ws + (1u << 20));
    bf16* aout = xw;
    // region B: qkv (bf16, 57.8MB) -> reused as proj-out f32 -> fc2-out f32
    char* Bp = ws + (1u << 20) + 19267584;
    bf16*  qkv  = (bf16*)Bp;
    float* pwin = (float*)Bp;
    float* fc2o = (float*)Bp;
    // region C: x1 f32; region D: xn2 bf16; region E: h1 bf16
    char* Cp = Bp + 57802752;
    float* x1  = (float*)Cp;
    bf16*  xn2 = (bf16*)(Cp + 38535168);
    bf16*  h1  = (bf16*)(Cp + 38535168 + 19267584);

    prep_w_k<<<576, 256, 0, stream>>>(qkvw, projw, f1w, f2w, qkv_wt, proj_wt, fc1_wt, fc2_wt);
    ln1_window_k<<<896, 256, 0, stream>>>(x, n1g, n1b, xw);
    gemm_k<192, 576, 0><<<392*9, 256, 0, stream>>>(xw, qkv_wt, qkvb, nullptr, qkv);
    attn_k<<<512*6, 256, 0, stream>>>(qkv, rpb, maskm, aout);
    gemm_k<192, 192, 1><<<392*3, 256, 0, stream>>>(aout, proj_wt, projb, nullptr, pwin);
    rev_res_ln2_k<<<896, 256, 0, stream>>>(x, pwin, n2g, n2b, x1, xn2);
    gemm_k<192, 768, 2><<<392*12, 256, 0, stream>>>(xn2, fc1_wt, f1b, nullptr, h1);
    gemm_k<768, 192, 3><<<392*3, 256, 0, stream>>>(h1, fc2_wt, f2b, x1, fc2o);
    transpose_out_k<<<896, 256, 0, stream>>>(fc2o, (float*)d_out);
}

// Round 3
// 296.509 us; speedup vs baseline: 1.3577x; 1.3577x over previous
//
#include <hip/hip_runtime.h>
#include <hip/hip_bf16.h>
#include <math.h>

#define DEV __device__ __forceinline__

typedef __bf16 bf16;
typedef __bf16 bf16x8 __attribute__((ext_vector_type(8)));
typedef float f32x4 __attribute__((ext_vector_type(4)));

DEV f32x4 zero4() { f32x4 z; z[0]=0.f; z[1]=0.f; z[2]=0.f; z[3]=0.f; return z; }

// ---------------------------------------------------------------------------
// Geometry: B=2, C=192, T=8, H=56, W=56; window (2,7,7) N=98; shift (1,3,3)
// windows: 4*8*8=256 per batch, B_=512; tokens M = 50176
// ---------------------------------------------------------------------------

// K0: transpose weights to (N,K) k-contiguous bf16
__global__ __launch_bounds__(256) void prep_w_k(
    const float* __restrict__ qw, const float* __restrict__ pw,
    const float* __restrict__ f1, const float* __restrict__ f2,
    bf16* __restrict__ qwt, bf16* __restrict__ pwt,
    bf16* __restrict__ f1t, bf16* __restrict__ f2t)
{
    int i = blockIdx.x * 256 + threadIdx.x;
    if (i < 576*192) { int n = i / 192, k = i % 192; qwt[i] = (bf16)qw[(size_t)k*576 + n]; }
    if (i < 192*192) { int n = i / 192, k = i % 192; pwt[i] = (bf16)pw[(size_t)k*192 + n]; }
    if (i < 768*192) { int n = i / 192, k = i % 192; f1t[i] = (bf16)f1[(size_t)k*768 + n]; }
    if (i < 192*768) { int n = i / 768, k = i % 768; f2t[i] = (bf16)f2[(size_t)k*192 + n]; }
}

// K0b: precompute bias table biasT[head][nq][nk_pad=112] f32,
// nk >= 98 -> -1e30 (softmax padding baked in).
__global__ __launch_bounds__(256) void prep_bias_k(
    const float* __restrict__ rpb, float* __restrict__ biasT)
{
    int i = blockIdx.x * 256 + threadIdx.x;
    if (i >= 6*98*112) return;
    int nk = i % 112; int t = i / 112; int nq = t % 98; int h = t / 98;
    float v;
    if (nk < 98) {
        int t1 = nq/49, r1 = nq%49, h1 = r1/7, w1 = r1%7;
        int t2 = nk/49, r2 = nk%49, h2 = r2/7, w2 = r2%7;
        int idx = (t1 - t2 + 1)*169 + (h1 - h2 + 6)*13 + (w1 - w2 + 6);
        v = rpb[idx*6 + h];
    } else {
        v = -1e30f;
    }
    biasT[i] = v;
}

// K1: LN1 + cyclic shift + window partition. grid = B*T*H = 896, block 256.
__global__ __launch_bounds__(256) void ln1_window_k(
    const float* __restrict__ x, const float* __restrict__ g,
    const float* __restrict__ bta, bf16* __restrict__ xw)
{
    __shared__ float tile[56*193];
    __shared__ float mu[56], rs[56];
    int blk = blockIdx.x;
    int bb = blk / 448; int r = blk % 448; int ts = r / 56; int hs = r % 56;
    int t = (ts + 1) & 7;
    int h = hs + 3; if (h >= 56) h -= 56;
    int tid = threadIdx.x;
    const float* xs = x + ((size_t)bb*1536 + t)*3136 + h*56;
    for (int e = tid; e < 192*56; e += 256) {
        int c = e / 56, w = e % 56;
        int wsp = w - 3; if (wsp < 0) wsp += 56;
        tile[wsp*193 + c] = xs[(size_t)c*25088 + w];
    }
    __syncthreads();
    if (tid < 56) {
        float s = 0.f, s2 = 0.f;
        for (int c = 0; c < 192; c++) { float v = tile[tid*193 + c]; s += v; s2 += v*v; }
        float m = s * (1.0f/192.0f);
        float var = s2 * (1.0f/192.0f) - m*m;
        mu[tid] = m; rs[tid] = rsqrtf(var + 1e-5f);
    }
    __syncthreads();
    int tb = ts >> 1, wt = ts & 1;
    int hb = hs / 7, wh = hs % 7;
    for (int e = tid; e < 56*192; e += 256) {
        int wpos = e / 192, c = e % 192;
        float v = (tile[wpos*193 + c] - mu[wpos]) * rs[wpos] * g[c] + bta[c];
        int wb = wpos / 7, ww = wpos % 7;
        int widx = bb*256 + tb*64 + hb*8 + wb;
        int n = wt*49 + wh*7 + ww;
        xw[((size_t)widx*98 + n)*192 + c] = (bf16)v;
    }
}

// Generic bf16 MFMA GEMM: C(M,NT) = A(M,KT) @ BT(NT,KT)^T + bias, M=50176.
template<int KT, int NT, int EPI>
__global__ __launch_bounds__(256) void gemm_k(
    const bf16* __restrict__ A, const bf16* __restrict__ BT,
    const float* __restrict__ bias, const float* __restrict__ resid,
    void* __restrict__ outp)
{
    __shared__ bf16 la[128*72];
    __shared__ bf16 lb[64*72];
    constexpr int NTILES = NT / 64;
    int bid = blockIdx.x;
    int m0 = (bid / NTILES) * 128;
    int n0 = (bid % NTILES) * 64;
    int tid = threadIdx.x;
    int lane = tid & 63;
    int wv = tid >> 6;
    int wr = wv >> 1, wc = wv & 1;
    int l15 = lane & 15, lg = lane >> 4;

    f32x4 acc[4][2];
    #pragma unroll
    for (int i = 0; i < 4; i++)
        #pragma unroll
        for (int j = 0; j < 2; j++) acc[i][j] = zero4();

    for (int kb = 0; kb < KT; kb += 64) {
        #pragma unroll
        for (int tt = 0; tt < 4; tt++) {
            int e = tid + tt*256;
            int row = e >> 3, ck = e & 7;
            *(bf16x8*)&la[row*72 + ck*8] =
                *(const bf16x8*)&A[(size_t)(m0 + row)*KT + kb + ck*8];
        }
        #pragma unroll
        for (int tt = 0; tt < 2; tt++) {
            int e = tid + tt*256;
            int row = e >> 3, ck = e & 7;
            *(bf16x8*)&lb[row*72 + ck*8] =
                *(const bf16x8*)&BT[(size_t)(n0 + row)*KT + kb + ck*8];
        }
        __syncthreads();
        #pragma unroll
        for (int ks = 0; ks < 64; ks += 32) {
            bf16x8 af[4], bfr[2];
            #pragma unroll
            for (int i = 0; i < 4; i++)
                af[i] = *(const bf16x8*)&la[(wr*64 + i*16 + l15)*72 + ks + lg*8];
            #pragma unroll
            for (int j = 0; j < 2; j++)
                bfr[j] = *(const bf16x8*)&lb[(wc*32 + j*16 + l15)*72 + ks + lg*8];
            #pragma unroll
            for (int i = 0; i < 4; i++)
                #pragma unroll
                for (int j = 0; j < 2; j++)
                    acc[i][j] = __builtin_amdgcn_mfma_f32_16x16x32_bf16(af[i], bfr[j], acc[i][j], 0, 0, 0);
        }
        __syncthreads();
    }

    #pragma unroll
    for (int i = 0; i < 4; i++) {
        #pragma unroll
        for (int j = 0; j < 2; j++) {
            #pragma unroll
            for (int r = 0; r < 4; r++) {
                int row = m0 + wr*64 + i*16 + lg*4 + r;
                int col = n0 + wc*32 + j*16 + l15;
                float v = acc[i][j][r] + bias[col];
                size_t oidx = (size_t)row * NT + col;
                if constexpr (EPI == 0) {
                    ((bf16*)outp)[oidx] = (bf16)v;
                } else if constexpr (EPI == 1) {
                    ((float*)outp)[oidx] = v;
                } else if constexpr (EPI == 2) {
                    float gl = 0.5f * v * (1.0f + erff(v * 0.70710678118654752f));
                    ((bf16*)outp)[oidx] = (bf16)gl;
                } else {
                    ((float*)outp)[oidx] = v + resid[oidx];
                }
            }
        }
    }
}

// K3: attention, one block per WINDOW (all 6 heads). grid = 512, block 448
// (7 waves). Tasks: 6 heads x 7 row-tiles = 42 = 7 waves x 6 tasks.
// LDS: K [112][200], V^T [192][136] XOR-swizzled, P per-wave [16][136].
// Correctness: VT is FULLY zeroed before staging (swizzled data cols and
// padding cols interleave; uninitialized LDS NaN x P=0 = NaN otherwise),
// with a barrier between zeroing and staging (no race).
__global__ __launch_bounds__(448) void attn_k(
    const bf16* __restrict__ qkv, const float* __restrict__ biasT,
    const float* __restrict__ maskm, bf16* __restrict__ aout)
{
    __shared__ bf16 Ks[112*200];
    __shared__ bf16 VT[192*136];
    __shared__ bf16 Pl[7*16*136];
    int b_ = blockIdx.x;
    int tid = threadIdx.x, lane = tid & 63, wv = tid >> 6;
    int l15 = lane & 15, lg = (lane >> 4) & 3;
    int wib = b_ & 255;
    const bf16* base = qkv + (size_t)b_*98*576;

    // ---- phase 0: zero all padding-sensitive LDS ----
    {
        unsigned int* vz = (unsigned int*)VT;                // all of VT
        for (int e = tid; e < (192*136)/2; e += 448) vz[e] = 0u;
        unsigned int* kz = (unsigned int*)(Ks + 98*200);     // K rows 98..111
        for (int e = tid; e < 1400; e += 448) kz[e] = 0u;
        unsigned int* pz = (unsigned int*)Pl;                // P cols 112..127
        for (int e = tid; e < 896; e += 448) {
            int w2 = e >> 7, rem = e & 127;
            int row = rem >> 3, cp = rem & 7;
            pz[(w2*16 + row)*68 + 56 + cp] = 0u;
        }
    }
    __syncthreads();
    // ---- phase 1: stage K (row-major, coalesced) ----
    for (int e = tid; e < 2352; e += 448) {
        int row = e / 24, ck = e % 24;
        *(bf16x8*)&Ks[row*200 + ck*8] =
            *(const bf16x8*)&base[(size_t)row*576 + 192 + ck*8];
    }
    // ---- stage V transposed, XOR swizzle: phys_col = key ^ ((d>>3 & 7)<<3) ----
    for (int i = tid; i < 2400; i += 448) {
        int low = i & 3, g = i >> 2;
        int ck = g % 24, nh = g / 24;
        int n = nh*4 + low;
        if (n < 98) {
            bf16x8 v8 = *(const bf16x8*)&base[(size_t)n*576 + 384 + ck*8];
            int pc = n ^ ((ck & 7) << 3);
            #pragma unroll
            for (int jj = 0; jj < 8; jj++)
                VT[(ck*8 + jj)*136 + pc] = v8[jj];
        }
    }
    __syncthreads();

    const float scale = 0.17677669529663687f;   // 32^-0.5
    bf16* Pw = Pl + wv*16*136;

    for (int ti = 0; ti < 6; ti++) {
        int t = wv*6 + ti;
        int head = t / 7, rt = t % 7;
        // Q fragment straight from global (each element used once)
        int qrow = rt*16 + l15; if (qrow > 97) qrow = 97;
        bf16x8 qf = *(const bf16x8*)&base[(size_t)qrow*576 + head*32 + lg*8];
        // ---- S = Q K^T ----
        f32x4 sacc[7];
        #pragma unroll
        for (int j = 0; j < 7; j++) sacc[j] = zero4();
        #pragma unroll
        for (int j = 0; j < 7; j++) {
            bf16x8 kf = *(const bf16x8*)&Ks[(j*16 + l15)*200 + head*32 + lg*8];
            sacc[j] = __builtin_amdgcn_mfma_f32_16x16x32_bf16(qf, kf, sacc[j], 0, 0, 0);
        }
        // ---- softmax (rows live in 16-lane groups; bias has -1e30 padding) ----
        #pragma unroll
        for (int r = 0; r < 4; r++) {
            int nq = rt*16 + lg*4 + r;
            int nqc = nq > 97 ? 97 : nq;
            const float* bb = biasT + (head*98 + nqc)*112;
            const float* mm = maskm + ((size_t)wib*98 + nqc)*98;
            float sv[7];
            float m = -1e30f;
            #pragma unroll
            for (int j = 0; j < 7; j++) {
                int nk = j*16 + l15;
                float v = sacc[j][r]*scale + bb[nk];
                if (nk < 98) v += mm[nk];
                sv[j] = v; m = fmaxf(m, v);
            }
            #pragma unroll
            for (int d = 1; d < 16; d <<= 1) m = fmaxf(m, __shfl_xor(m, d));
            float sum = 0.f;
            #pragma unroll
            for (int j = 0; j < 7; j++) { sv[j] = __expf(sv[j] - m); sum += sv[j]; }
            #pragma unroll
            for (int d = 1; d < 16; d <<= 1) sum += __shfl_xor(sum, d);
            float inv = 1.0f / sum;
            #pragma unroll
            for (int j = 0; j < 7; j++)
                Pw[(lg*4 + r)*136 + j*16 + l15] = (bf16)(sv[j]*inv);
        }
        // ---- O = P V ----
        #pragma unroll
        for (int dt = 0; dt < 2; dt++) {
            int drow = head*32 + dt*16 + l15;
            int xr = ((drow >> 3) & 7) << 3;
            f32x4 oacc = zero4();
            #pragma unroll
            for (int kc = 0; kc < 4; kc++) {
                bf16x8 pf = *(const bf16x8*)&Pw[l15*136 + kc*32 + lg*8];
                bf16x8 vf = *(const bf16x8*)&VT[drow*136 + ((kc*32 + lg*8) ^ xr)];
                oacc = __builtin_amdgcn_mfma_f32_16x16x32_bf16(pf, vf, oacc, 0, 0, 0);
            }
            #pragma unroll
            for (int r = 0; r < 4; r++) {
                int row = rt*16 + lg*4 + r;
                if (row < 98)
                    aout[((size_t)b_*98 + row)*192 + head*32 + dt*16 + l15] = (bf16)oacc[r];
            }
        }
    }
}

// K5: window reverse + roll-back + residual(x) + LN2. grid 896.
__global__ __launch_bounds__(256) void rev_res_ln2_k(
    const float* __restrict__ x, const float* __restrict__ pw,
    const float* __restrict__ g2, const float* __restrict__ b2,
    float* __restrict__ x1, bf16* __restrict__ xn2)
{
    __shared__ float tile[56*193];
    __shared__ float mu[56], rs[56];
    int blk = blockIdx.x;
    int bb = blk / 448; int r = blk % 448; int t = r / 56; int h = r % 56;
    int ts = (t + 7) & 7;
    int hs = h - 3; if (hs < 0) hs += 56;
    int tid = threadIdx.x;
    const float* xs = x + ((size_t)bb*1536 + t)*3136 + h*56;
    for (int e = tid; e < 192*56; e += 256) {
        int c = e / 56, w = e % 56;
        tile[w*193 + c] = xs[(size_t)c*25088 + w];
    }
    __syncthreads();
    int tb = ts >> 1, wt = ts & 1, hb = hs / 7, wh = hs % 7;
    for (int e = tid; e < 56*192; e += 256) {
        int w = e / 192, c = e % 192;
        int wsp = w - 3; if (wsp < 0) wsp += 56;
        int wb = wsp / 7, ww = wsp % 7;
        size_t tok = (size_t)(bb*256 + tb*64 + hb*8 + wb)*98 + wt*49 + wh*7 + ww;
        tile[w*193 + c] += pw[tok*192 + c];
    }
    __syncthreads();
    if (tid < 56) {
        float s = 0.f, s2 = 0.f;
        for (int c = 0; c < 192; c++) { float v = tile[tid*193 + c]; s += v; s2 += v*v; }
        float m = s * (1.0f/192.0f);
        float var = s2 * (1.0f/192.0f) - m*m;
        mu[tid] = m; rs[tid] = rsqrtf(var + 1e-5f);
    }
    __syncthreads();
    size_t tok0 = ((size_t)(bb*8 + t)*56 + h)*56;
    for (int e = tid; e < 56*192; e += 256) {
        int w = e / 192, c = e % 192;
        float v = tile[w*193 + c];
        x1[(tok0 + w)*192 + c] = v;
        xn2[(tok0 + w)*192 + c] = (bf16)((v - mu[w]) * rs[w] * g2[c] + b2[c]);
    }
}

// K8: channel-last -> channel-first transpose of final x2. grid 896.
__global__ __launch_bounds__(256) void transpose_out_k(
    const float* __restrict__ xin, float* __restrict__ out)
{
    __shared__ float tile[192*57];
    int blk = blockIdx.x;
    int bb = blk / 448; int r = blk % 448; int t = r / 56; int h = r % 56;
    int tid = threadIdx.x;
    const float* rowp = xin + ((size_t)(bb*8 + t)*56 + h)*56*192;
    for (int e = tid; e < 56*192; e += 256) {
        int w = e / 192, c = e % 192;
        tile[c*57 + w] = rowp[e];
    }
    __syncthreads();
    float* op = out + (size_t)bb*192*25088 + (size_t)t*3136 + h*56;
    for (int e = tid; e < 192*56; e += 256) {
        int c = e / 56, w = e % 56;
        op[(size_t)c*25088 + w] = tile[c*57 + w];
    }
}

// ---------------------------------------------------------------------------
extern "C" void kernel_launch(void* const* d_in, const int* in_sizes, int n_in,
                              void* d_out, int out_size, void* d_ws, size_t ws_size,
                              hipStream_t stream)
{
    const float* x     = (const float*)d_in[0];
    const float* maskm = (const float*)d_in[1];
    const float* n1g   = (const float*)d_in[2];
    const float* n1b   = (const float*)d_in[3];
    const float* qkvw  = (const float*)d_in[4];
    const float* qkvb  = (const float*)d_in[5];
    const float* projw = (const float*)d_in[6];
    const float* projb = (const float*)d_in[7];
    const float* rpb   = (const float*)d_in[8];
    const float* n2g   = (const float*)d_in[9];
    const float* n2b   = (const float*)d_in[10];
    const float* f1w   = (const float*)d_in[11];
    const float* f1b   = (const float*)d_in[12];
    const float* f2w   = (const float*)d_in[13];
    const float* f2b   = (const float*)d_in[14];

    char* ws = (char*)d_ws;
    // weights (transposed bf16) + bias table
    bf16*  qkv_wt  = (bf16*)(ws + 0);          // 221184
    bf16*  proj_wt = (bf16*)(ws + 221184);     // 73728
    bf16*  fc1_wt  = (bf16*)(ws + 294912);     // 294912
    bf16*  fc2_wt  = (bf16*)(ws + 589824);     // 294912
    float* biasT   = (float*)(ws + 884736);    // 6*98*112*4 = 263424
    // region A: xw (bf16, 19.27MB) -> reused as attn_out
    bf16* xw   = (bf16*)(ws + 1179648);
    bf16* aout = xw;
    // region B: qkv (bf16, 57.8MB) -> reused as proj-out f32 -> fc2-out f32
    char* Bp = ws + 1179648 + 19267584;
    bf16*  qkv  = (bf16*)Bp;
    float* pwin = (float*)Bp;
    float* fc2o = (float*)Bp;
    // region C: x1 f32; region D: xn2 bf16; region E: h1 bf16
    char* Cp = Bp + 57802752;
    float* x1  = (float*)Cp;
    bf16*  xn2 = (bf16*)(Cp + 38535168);
    bf16*  h1  = (bf16*)(Cp + 38535168 + 19267584);

    prep_w_k<<<576, 256, 0, stream>>>(qkvw, projw, f1w, f2w, qkv_wt, proj_wt, fc1_wt, fc2_wt);
    prep_bias_k<<<258, 256, 0, stream>>>(rpb, biasT);
    ln1_window_k<<<896, 256, 0, stream>>>(x, n1g, n1b, xw);
    gemm_k<192, 576, 0><<<392*9, 256, 0, stream>>>(xw, qkv_wt, qkvb, nullptr, qkv);
    attn_k<<<512, 448, 0, stream>>>(qkv, biasT, maskm, aout);
    gemm_k<192, 192, 1><<<392*3, 256, 0, stream>>>(aout, proj_wt, projb, nullptr, pwin);
    rev_res_ln2_k<<<896, 256, 0, stream>>>(x, pwin, n2g, n2b, x1, xn2);
    gemm_k<192, 768, 2><<<392*12, 256, 0, stream>>>(xn2, fc1_wt, f1b, nullptr, h1);
    gemm_k<768, 192, 3><<<392*3, 256, 0, stream>>>(h1, fc2_wt, f2b, x1, fc2o);
    transpose_out_k<<<896, 256, 0, stream>>>(fc2o, (float*)d_out);
}